// Round 10
// baseline (288.093 us; speedup 1.0000x reference)
//
#include <hip/hip_runtime.h>
#include <stdint.h>

// out[b,s,u] = (LN(x) @ ternary(W)) * mean|W|   (reference's gamma absmax cancels)
// Round 10: split pipeline (champion) + 8-phase counted-vmcnt gemm_k (m201 port):
// 256x256 tile, BK=64, 8 waves, TRIPLE-buffered LDS (96 KB) so vmcnt(4) keeps the
// next-next tile's loads in flight across raw s_barrier (never drain to 0).
// x: (4,8192,1024) fp32 -> M=32768, K=1024, N=1024, out fp32.

#define M_ROWS 32768
#define KDIM 1024
#define NDIM 1024

typedef int   v4i  __attribute__((ext_vector_type(4)));
typedef int   v16i __attribute__((ext_vector_type(16)));

#define MFMA_I8 __builtin_amdgcn_mfma_i32_32x32x32_i8

__device__ __forceinline__ void async16(const void* g, void* l) {
    __builtin_amdgcn_global_load_lds((const __attribute__((address_space(1))) uint32_t*)g,
                                     (__attribute__((address_space(3))) uint32_t*)l,
                                     16, 0, 0);
}

// ---------------- kernel 1: |w| partial sums (no atomics, no memset) ------------
__global__ __launch_bounds__(256) void absum_k(const float* __restrict__ w,
                                               float* __restrict__ partials) {
    int idx = blockIdx.x * 256 + threadIdx.x;
    float4 v = ((const float4*)w)[idx];
    float s = fabsf(v.x) + fabsf(v.y) + fabsf(v.z) + fabsf(v.w);
    #pragma unroll
    for (int o = 32; o; o >>= 1) s += __shfl_xor(s, o);
    __shared__ float p[4];
    if ((threadIdx.x & 63) == 0) p[threadIdx.x >> 6] = s;
    __syncthreads();
    if (threadIdx.x == 0) partials[blockIdx.x] = p[0] + p[1] + p[2] + p[3];
}

// ---------------- kernel 2: ternarize + transpose -> wqT[n][k] i8 ---------------
__global__ __launch_bounds__(256) void quant_k(const float* __restrict__ w,
                                               const float* __restrict__ partials,
                                               char* __restrict__ wqT,
                                               float* __restrict__ wsum) {
    int t = threadIdx.x;
    float s = partials[t] + partials[t + 256] + partials[t + 512] + partials[t + 768];
    #pragma unroll
    for (int o = 32; o; o >>= 1) s += __shfl_xor(s, o);
    __shared__ float ps[4];
    if ((t & 63) == 0) ps[t >> 6] = s;
    __syncthreads();
    float total = ps[0] + ps[1] + ps[2] + ps[3];
    if (blockIdx.x == 0 && t == 0) wsum[0] = total;
    float beta = total * (1.0f / 1048576.0f);
    float inv  = 1.0f / (beta + 1e-5f);

    __shared__ char sT[64 * 80];           // [n][k], stride 80 (16B-aligned rows)
    int k0 = (blockIdx.x >> 4) * 64, n0 = (blockIdx.x & 15) * 64;
    int n_l = t & 63;
    #pragma unroll
    for (int r = 0; r < 16; ++r) {
        int k_l = (t >> 6) * 16 + r;
        float q = rintf(w[(size_t)(k0 + k_l) * NDIM + n0 + n_l] * inv);
        q = fminf(1.0f, fmaxf(-1.0f, q));
        sT[n_l * 80 + k_l] = (char)(int)q;
    }
    __syncthreads();
    int nn = t >> 2, c = t & 3;
    v4i val = *(const v4i*)&sT[nn * 80 + c * 16];
    *(v4i*)&wqT[(size_t)(n0 + nn) * KDIM + k0 + c * 16] = val;
}

// ---------------- kernel 3: LN + per-row i8 quant, wave-per-row, one pass -------
__global__ __launch_bounds__(256) void ln_q_k(const float* __restrict__ x,
                                              const float* __restrict__ g,
                                              const float* __restrict__ b,
                                              char* __restrict__ xq,
                                              float* __restrict__ rscale) {
    int tid = threadIdx.x;
    int lane = tid & 63;
    int row = blockIdx.x * 4 + (tid >> 6);
    const float4* xr = (const float4*)(x + (size_t)row * KDIM);
    float4 v[4];
    #pragma unroll
    for (int j = 0; j < 4; ++j) v[j] = xr[lane + 64 * j];
    float s = 0.f, ss = 0.f;
    #pragma unroll
    for (int j = 0; j < 4; ++j) {
        s  += v[j].x + v[j].y + v[j].z + v[j].w;
        ss += v[j].x * v[j].x + v[j].y * v[j].y + v[j].z * v[j].z + v[j].w * v[j].w;
    }
    #pragma unroll
    for (int o = 32; o; o >>= 1) { s += __shfl_xor(s, o); ss += __shfl_xor(ss, o); }
    float mu  = s * (1.0f / 1024.0f);
    float var = ss * (1.0f / 1024.0f) - mu * mu;
    float rs  = rsqrtf(var + 1e-3f);        // keras LN eps
    float xn[16];
    float mx = 0.f;
    #pragma unroll
    for (int j = 0; j < 4; ++j) {
        int p = lane + 64 * j;
        float4 gg = ((const float4*)g)[p];
        float4 bb = ((const float4*)b)[p];
        xn[4*j+0] = (v[j].x - mu) * rs * gg.x + bb.x;
        xn[4*j+1] = (v[j].y - mu) * rs * gg.y + bb.y;
        xn[4*j+2] = (v[j].z - mu) * rs * gg.z + bb.z;
        xn[4*j+3] = (v[j].w - mu) * rs * gg.w + bb.w;
        #pragma unroll
        for (int e = 0; e < 4; ++e) mx = fmaxf(mx, fabsf(xn[4*j+e]));
    }
    #pragma unroll
    for (int o = 32; o; o >>= 1) mx = fmaxf(mx, __shfl_xor(mx, o));
    mx = fmaxf(mx, 1e-20f);
    float scl = mx * (1.0f / 127.0f);
    float inv = 127.0f / mx;
    if (lane == 0) rscale[row] = scl;
    #pragma unroll
    for (int j = 0; j < 4; ++j) {
        char4 c;
        c.x = (char)(int)rintf(xn[4*j+0] * inv);
        c.y = (char)(int)rintf(xn[4*j+1] * inv);
        c.z = (char)(int)rintf(xn[4*j+2] * inv);
        c.w = (char)(int)rintf(xn[4*j+3] * inv);
        *(char4*)(xq + (size_t)row * KDIM + (lane + 64 * j) * 4) = c;
    }
}

// ---------------- kernel 4: 8-phase counted-vmcnt i8 GEMM -----------------------
// A: [M][K] i8, B: [N][K] i8, out [M][N] f32. Tile 256x256, BK=64, 16 K-tiles.
// 512 thr = 8 waves (2M x 4N); wave = 128m x 64n = 4x2 of 32x32x32 i8 MFMA.
// LDS: 3 buffers x (A 16KB + B 16KB) = 96 KB. Superrow layout: 2 rows packed per
// 128-B LDS row (8 chunks of 16B), chunk-XOR swizzle by superrow&7 (validated geom).
// Schedule per K-tile t (4 phases): each phase { 4x ds_read_b128 ; 1x async16 half
// of tile t+2 into buf[(t+2)%3] ; s_barrier ; setprio(1) 4x MFMA setprio(0) ;
// s_barrier }. Tile end: s_waitcnt vmcnt(4) (tile t+1's 4 loads retired, tile
// t+2's 4 stay IN FLIGHT) + s_barrier + sched_barrier(0). Race-free: buf[(t+2)%3]
// was last read at tile t-1, whose reads finished at t-1's last phase barrier.
__global__ __launch_bounds__(512) void gemm_k(const char* __restrict__ A,
                                              const char* __restrict__ B,
                                              const float* __restrict__ wsum,
                                              const float* __restrict__ rscale,
                                              float* __restrict__ out) {
    __shared__ char sA[3][16384];   // 128 superrows x 128 B each
    __shared__ char sB[3][16384];

    int tid = threadIdx.x;
    int w = tid >> 6, lane = tid & 63;
    int half = lane >> 5, l31 = lane & 31;
    int wm = w >> 2, wn = w & 3;                 // 2M x 4N waves

    int xcd   = blockIdx.x & 7;                  // 512 blocks = 8 XCD x 64
    int local = blockIdx.x >> 3;                 // 0..63
    int bm0 = (xcd * 16 + (local >> 2)) * 256;   // disjoint M-panel per XCD
    int bn0 = (local & 3) * 256;                 // bn innermost -> A L2 reuse

    // staging lane geometry (validated): slab = 8 superrows x 128 B per wave-round
    int r_sub = lane >> 3;                       // superrow within slab
    int pc    = lane & 7;                        // stored chunk slot
    int cch   = pc ^ r_sub;                      // source chunk (sr&7 == r_sub)

    // ds_read lane geometry: superrow low = l31>>1, chunk = (l31&1)*4 + kh*2 + half
    int srl  = l31 >> 1;
    int cb   = ((l31 & 1) << 2) | half;          // chunk base (kh=0)
    int sxor = srl & 7;

    // stage half h (0,1 = A sr-halves; 2,3 = B sr-halves) of K-tile tt into buf i
    #define STAGE(h, tt, bi) do { \
        int hh_ = (h) & 1; \
        int sr_ = hh_ * 64 + w * 8 + r_sub; \
        int row_ = 2 * sr_ + (cch >> 2); \
        size_t go_ = (size_t)row_ * KDIM + (tt) * 64 + (cch & 3) * 16; \
        if ((h) < 2) async16(A + (size_t)bm0 * KDIM + go_, &sA[bi][hh_ * 8192 + w * 1024]); \
        else         async16(B + (size_t)bn0 * KDIM + go_, &sB[bi][hh_ * 8192 + w * 1024]); \
    } while (0)

    v16i acc[4][2] = {};

    // prologue: tiles 0 and 1 fully staged; wait for tile 0 (keep tile 1 in flight)
    #pragma unroll
    for (int h = 0; h < 4; ++h) STAGE(h, 0, 0);
    #pragma unroll
    for (int h = 0; h < 4; ++h) STAGE(h, 1, 1);
    asm volatile("s_waitcnt vmcnt(4)" ::: "memory");
    __builtin_amdgcn_s_barrier();
    __builtin_amdgcn_sched_barrier(0);

    int rb = 0, wb = 2;
    #pragma unroll 1
    for (int t = 0; t < 16; ++t) {
        const char* cA = sA[rb];
        const char* cB = sB[rb];
        #pragma unroll
        for (int p = 0; p < 4; ++p) {
            const int ipair = p & 1, kh = p >> 1;
            int slot = ((cb | (kh << 1)) ^ sxor) << 4;
            v4i af0 = *(const v4i*)&cA[(wm * 64 + (ipair * 2 + 0) * 16 + srl) * 128 + slot];
            v4i af1 = *(const v4i*)&cA[(wm * 64 + (ipair * 2 + 1) * 16 + srl) * 128 + slot];
            v4i bf0 = *(const v4i*)&cB[(wn * 32 +  0 + srl) * 128 + slot];
            v4i bf1 = *(const v4i*)&cB[(wn * 32 + 16 + srl) * 128 + slot];
            if (t < 14) STAGE(p, t + 2, wb);
            __builtin_amdgcn_s_barrier();
            __builtin_amdgcn_s_setprio(1);
            acc[ipair * 2 + 0][0] = MFMA_I8(af0, bf0, acc[ipair * 2 + 0][0], 0, 0, 0);
            acc[ipair * 2 + 0][1] = MFMA_I8(af0, bf1, acc[ipair * 2 + 0][1], 0, 0, 0);
            acc[ipair * 2 + 1][0] = MFMA_I8(af1, bf0, acc[ipair * 2 + 1][0], 0, 0, 0);
            acc[ipair * 2 + 1][1] = MFMA_I8(af1, bf1, acc[ipair * 2 + 1][1], 0, 0, 0);
            __builtin_amdgcn_s_setprio(0);
            __builtin_amdgcn_s_barrier();
        }
        if (t < 15) {
            if (t == 14) asm volatile("s_waitcnt vmcnt(0)" ::: "memory");
            else         asm volatile("s_waitcnt vmcnt(4)" ::: "memory");
            __builtin_amdgcn_s_barrier();
            __builtin_amdgcn_sched_barrier(0);
        }
        rb = (rb == 2) ? 0 : rb + 1;
        wb = (wb == 2) ? 0 : wb + 1;
    }
    #undef STAGE

    float beta = wsum[0] * (1.0f / 1048576.0f);
    #pragma unroll
    for (int i = 0; i < 4; ++i) {
        #pragma unroll
        for (int r = 0; r < 16; ++r) {
            // C/D 32x32: col = lane&31, row = (r&3) + 8*(r>>2) + 4*(lane>>5)
            int mrow = bm0 + wm * 128 + i * 32 + (r & 3) + 8 * (r >> 2) + 4 * half;
            float sc = rscale[mrow] * beta;
            #pragma unroll
            for (int j = 0; j < 2; ++j) {
                int ncol = bn0 + wn * 64 + j * 32 + l31;
                out[(size_t)mrow * NDIM + ncol] = (float)acc[i][j][r] * sc;
            }
        }
    }
}

extern "C" void kernel_launch(void* const* d_in, const int* in_sizes, int n_in,
                              void* d_out, int out_size, void* d_ws, size_t ws_size,
                              hipStream_t stream) {
    const float* x        = (const float*)d_in[0];   // 4*8192*1024
    const float* weight   = (const float*)d_in[1];   // 1024*1024
    const float* ln_gamma = (const float*)d_in[2];   // 1024
    const float* ln_beta  = (const float*)d_in[3];   // 1024
    float* out = (float*)d_out;

    // ws layout: [0,4) wsum | [4K, 8K) partials(1024 f32) | [8K, 136K) rscale(32768 f32)
    //            [256K, 256K+1M) wqT i8 | [2M, 2M+32M) xq i8
    float* wsum     = (float*)d_ws;
    float* partials = (float*)((char*)d_ws + 4096);
    float* rscale   = (float*)((char*)d_ws + 8192);
    char*  wqT      = (char*)d_ws + (1u << 18);
    char*  xq       = (char*)d_ws + (1u << 21);

    absum_k<<<1024, 256, 0, stream>>>(weight, partials);
    quant_k<<<256, 256, 0, stream>>>(weight, partials, wqT, wsum);
    ln_q_k<<<M_ROWS / 4, 256, 0, stream>>>(x, ln_gamma, ln_beta, xq, rscale);
    gemm_k<<<(M_ROWS / 256) * (NDIM / 256), 512, 0, stream>>>(xq, wqT, wsum, rscale, out);
}